// Round 1
// baseline (10769.064 us; speedup 1.0000x reference)
//
#include <hip/hip_runtime.h>

#define T_STEPS 4096
#define BATCH   64
#define INDIM   4
#define H       256
#define OUTD    2

__device__ __forceinline__ float fast_tanh(float x) {
    float ax = fabsf(x);
    float e  = __expf(-2.0f * ax);                       // v_exp_f32 path
    float r  = (1.0f - e) * __builtin_amdgcn_rcpf(1.0f + e);
    return copysignf(r, x);
}

__global__ __launch_bounds__(256, 1)
void elman_kernel(const float* __restrict__ input,
                  const float* __restrict__ Wi,
                  const float* __restrict__ bi,
                  const float* __restrict__ Wh,
                  const float* __restrict__ bh,
                  const float* __restrict__ Wf,
                  const float* __restrict__ bf,
                  float* __restrict__ out)
{
    const int b    = blockIdx.x;    // batch element: independent recurrence
    const int hi   = threadIdx.x;   // hidden row this thread owns
    const int wv   = hi >> 6;       // wave id 0..3
    const int lane = hi & 63;

    __shared__ float h_lds[2][H];   // double-buffered hidden state broadcast
    __shared__ float red[2][4][2];  // double-buffered out-head partials

    // Wh row -> registers (256 VGPRs; 1 wave/SIMD, no spill expected <450)
    float4 wh[H / 4];
    #pragma unroll
    for (int j = 0; j < H / 4; ++j)
        wh[j] = *(const float4*)(Wh + (size_t)hi * H + 4 * j);

    const float4 wiv  = *(const float4*)(Wi + hi * INDIM);
    const float  bias = bi[hi] + bh[hi];
    const float  wf0  = Wf[hi];
    const float  wf1  = Wf[H + hi];
    const float  bf0  = bf[0], bf1 = bf[1];

    h_lds[0][hi] = 0.0f;
    __syncthreads();

    // wave-uniform input vector, software-prefetched one step ahead
    float4 xcur = *(const float4*)(input + (size_t)b * INDIM);  // step 0

    for (int step = 0; step < T_STEPS; ++step) {
        const int p = step & 1;

        int s2 = step + 1; if (s2 >= T_STEPS) s2 = T_STEPS - 1;
        float4 xnext = *(const float4*)(input + ((size_t)s2 * BATCH + b) * INDIM);

        // ---- recurrent dot: 256 FMAs, 4 independent accumulators ----
        const float4* hv = (const float4*)h_lds[p];
        float4 acc = make_float4(0.f, 0.f, 0.f, 0.f);
        #pragma unroll
        for (int j = 0; j < H / 4; ++j) {
            float4 v = hv[j];          // uniform-address LDS broadcast read
            acc.x = fmaf(wh[j].x, v.x, acc.x);
            acc.y = fmaf(wh[j].y, v.y, acc.y);
            acc.z = fmaf(wh[j].z, v.z, acc.z);
            acc.w = fmaf(wh[j].w, v.w, acc.w);
        }
        float pre = (acc.x + acc.y) + (acc.z + acc.w);
        pre += xcur.x * wiv.x + xcur.y * wiv.y + xcur.z * wiv.z + xcur.w * wiv.w;
        pre += bias;
        const float hn = fast_tanh(pre);

        h_lds[p ^ 1][hi] = hn;

        // ---- fused output head: cross-lane reduce of hn*Wf ----
        float p0 = hn * wf0;
        float p1 = hn * wf1;
        #pragma unroll
        for (int m = 32; m >= 1; m >>= 1) {
            p0 += __shfl_xor(p0, m, 64);
            p1 += __shfl_xor(p1, m, 64);
        }
        if (lane == 0) { red[p][wv][0] = p0; red[p][wv][1] = p1; }

        // finalize previous step's output (red[p^1] is stable: written
        // before last barrier, not overwritten until after next barrier)
        if (hi == 0 && step > 0) {
            const int q = p ^ 1;
            float o0 = (red[q][0][0] + red[q][1][0]) + (red[q][2][0] + red[q][3][0]);
            float o1 = (red[q][0][1] + red[q][1][1]) + (red[q][2][1] + red[q][3][1]);
            float* op = out + ((size_t)(step - 1) * BATCH + b) * OUTD;
            op[0] = fast_tanh(o0 + bf0);
            op[1] = fast_tanh(o1 + bf1);
        }

        __syncthreads();
        xcur = xnext;
    }

    if (hi == 0) {
        const int q = (T_STEPS - 1) & 1;
        float o0 = (red[q][0][0] + red[q][1][0]) + (red[q][2][0] + red[q][3][0]);
        float o1 = (red[q][0][1] + red[q][1][1]) + (red[q][2][1] + red[q][3][1]);
        float* op = out + ((size_t)(T_STEPS - 1) * BATCH + b) * OUTD;
        op[0] = fast_tanh(o0 + bf0);
        op[1] = fast_tanh(o1 + bf1);
    }
}

extern "C" void kernel_launch(void* const* d_in, const int* in_sizes, int n_in,
                              void* d_out, int out_size, void* d_ws, size_t ws_size,
                              hipStream_t stream) {
    const float* input = (const float*)d_in[0];
    // d_in[1] = target (unused by forward)
    const float* Wi = (const float*)d_in[2];
    const float* bi = (const float*)d_in[3];
    const float* Wh = (const float*)d_in[4];
    const float* bh = (const float*)d_in[5];
    const float* Wf = (const float*)d_in[6];
    const float* bf = (const float*)d_in[7];
    float* out = (float*)d_out;

    elman_kernel<<<dim3(BATCH), dim3(256), 0, stream>>>(
        input, Wi, bi, Wh, bh, Wf, bf, out);
}

// Round 2
// 3303.899 us; speedup vs baseline: 3.2595x; 3.2595x over previous
//
#include <hip/hip_runtime.h>

#define T_STEPS 4096
#define BATCH   64
#define INDIM   4
#define H       256
#define OUTD    2
#define CHUNK   32          // h-history ring depth (LDS)
#define QPAD    68          // floats per k-quarter in LDS: 64 + 4 pad (bank derotation)
#define HROW    (4*QPAD)    // 272 floats per stored h vector

__device__ __forceinline__ float fast_tanh(float x) {
    float ax = fabsf(x);
    float e  = __expf(-2.0f * ax);
    float r  = (1.0f - e) * __builtin_amdgcn_rcpf(1.0f + e);
    return copysignf(r, x);
}

// 1024 threads = 16 waves = 4 waves/SIMD (1 block/CU). VGPR cap 128:
// per-thread weights are only 64 floats (quarter row) -> no spill.
__global__ __launch_bounds__(1024, 4)
void elman_kernel(const float* __restrict__ input,
                  const float* __restrict__ Wi,
                  const float* __restrict__ bi,
                  const float* __restrict__ Wh,
                  const float* __restrict__ bh,
                  const float* __restrict__ Wf,
                  const float* __restrict__ bf,
                  float* __restrict__ out)
{
    const int b  = blockIdx.x;     // batch element (independent recurrence)
    const int t  = threadIdx.x;
    const int r  = t >> 2;         // hidden row 0..255
    const int kq = t & 3;          // k-quarter 0..3

    __shared__ float h_hist[CHUNK][HROW];  // ring of padded h vectors (~34.8 KB)
    __shared__ float wf_lds[OUTD * H];     // output-head weights (2 KB)

    // --- per-thread quarter-row of Wh: 16 float4 = 64 VGPRs ---
    float4 wh[16];
    {
        const float* wrow = Wh + (size_t)r * H + kq * 64;
        #pragma unroll
        for (int j = 0; j < 16; ++j)
            wh[j] = *(const float4*)(wrow + 4 * j);
    }

    const float4 wiv  = *(const float4*)(Wi + r * INDIM);
    const float  bias = bi[r] + bh[r];
    const float  bf0  = bf[0], bf1 = bf[1];

    if (t < OUTD * H) wf_lds[t] = Wf[t];
    if (t < H)        h_hist[CHUNK - 1][(t >> 6) * QPAD + (t & 63)] = 0.0f; // h0 = 0
    __syncthreads();

    // wave-uniform x vector, prefetched one step ahead
    float4 xcur = *(const float4*)(input + (size_t)b * INDIM);  // step 0

    for (int chunk = 0; chunk < T_STEPS / CHUNK; ++chunk) {
        #pragma unroll 1
        for (int i = 0; i < CHUNK; ++i) {
            const int step = chunk * CHUNK + i;
            int s2 = step + 1; if (s2 >= T_STEPS) s2 = T_STEPS - 1;
            float4 xnext = *(const float4*)(input + ((size_t)s2 * BATCH + b) * INDIM);

            // h quarter, broadcast within kq-group; QPAD spreads the 4 groups'
            // lines across disjoint bank quads (no 4-way conflict)
            const float* hb = &h_hist[(i + CHUNK - 1) & (CHUNK - 1)][kq * QPAD];

            float4 acc = make_float4(0.f, 0.f, 0.f, 0.f);
            #pragma unroll
            for (int j = 0; j < 16; ++j) {
                float4 hv = *(const float4*)(hb + 4 * j);
                acc.x = fmaf(wh[j].x, hv.x, acc.x);
                acc.y = fmaf(wh[j].y, hv.y, acc.y);
                acc.z = fmaf(wh[j].z, hv.z, acc.z);
                acc.w = fmaf(wh[j].w, hv.w, acc.w);
            }
            float pre = (acc.x + acc.y) + (acc.z + acc.w);
            if (kq == 0)
                pre += xcur.x * wiv.x + xcur.y * wiv.y +
                       xcur.z * wiv.z + xcur.w * wiv.w + bias;

            // sum the 4 k-quarter partials (lanes t, t^1, t^2 within group)
            pre += __shfl_xor(pre, 1, 64);
            pre += __shfl_xor(pre, 2, 64);

            const float hn = fast_tanh(pre);
            if (kq == 0)
                h_hist[i][(r >> 6) * QPAD + (r & 63)] = hn;

            xcur = xnext;
            __syncthreads();
        }

        // --- deferred output head for this chunk (amortized ~0.5 cyc/step) ---
        {
            const int task = t >> 4;      // 0..63 : (step-in-chunk, out-idx)
            const int s    = task >> 1;   // 0..31
            const int o    = task & 1;
            const int sub  = t & 15;      // 16-float k-segment
            const int q    = sub >> 2;
            const float* hp = &h_hist[s][q * QPAD + (sub & 3) * 16];
            const float* wp = &wf_lds[o * H + sub * 16];

            float a0 = 0.f, a1 = 0.f, a2 = 0.f, a3 = 0.f;
            #pragma unroll
            for (int j = 0; j < 4; ++j) {
                float4 hv = *(const float4*)(hp + 4 * j);
                float4 wv = *(const float4*)(wp + 4 * j);
                a0 = fmaf(hv.x, wv.x, a0);
                a1 = fmaf(hv.y, wv.y, a1);
                a2 = fmaf(hv.z, wv.z, a2);
                a3 = fmaf(hv.w, wv.w, a3);
            }
            float sum = (a0 + a1) + (a2 + a3);
            sum += __shfl_xor(sum, 1, 64);
            sum += __shfl_xor(sum, 2, 64);
            sum += __shfl_xor(sum, 4, 64);
            sum += __shfl_xor(sum, 8, 64);

            if (sub == 0) {
                const float ob = (o == 0) ? bf0 : bf1;
                out[((size_t)(chunk * CHUNK + s) * BATCH + b) * OUTD + o] =
                    fast_tanh(sum + ob);
            }
            __syncthreads();  // protect h_hist before next chunk overwrites
        }
    }
}

extern "C" void kernel_launch(void* const* d_in, const int* in_sizes, int n_in,
                              void* d_out, int out_size, void* d_ws, size_t ws_size,
                              hipStream_t stream) {
    const float* input = (const float*)d_in[0];
    // d_in[1] = target (unused by forward)
    const float* Wi = (const float*)d_in[2];
    const float* bi = (const float*)d_in[3];
    const float* Wh = (const float*)d_in[4];
    const float* bh = (const float*)d_in[5];
    const float* Wf = (const float*)d_in[6];
    const float* bf = (const float*)d_in[7];
    float* out = (float*)d_out;

    elman_kernel<<<dim3(BATCH), dim3(1024), 0, stream>>>(
        input, Wi, bi, Wh, bh, Wf, bf, out);
}